// Round 7
// baseline (24910.895 us; speedup 1.0000x reference)
//
#include <hip/hip_runtime.h>
#include <math.h>

#define T_STEPS 4096
#define HDIM    2048
#define KDIM    2048
#define NG      8192      // 4*H
#define NREC    2048      // records per slot: one {h,tag} per h element
#define NSLOT   3         // 3-slot rotation (lap safety without counters)

typedef unsigned long long ull;

// ---------------- init ----------------
// recs[3][NREC]: tagged h records, 8B each: {lo: h bits, hi: tag}.
// Producer of step t writes tag t+1 into slot t%3; consumer at step t
// polls slot (t-1)%3 for tag t. Slot 2 = h0 (tag 0); slots 0,1 sentinel.
__global__ void init_ws5(const float* __restrict__ h0,
                         uint2* __restrict__ recs) {    // [NSLOT][NREC]
    int d = blockIdx.x * blockDim.x + threadIdx.x;
    if (d < NSLOT * NREC) {
        int slot = d >> 11;          // NREC = 2048
        int r = d & (NREC - 1);
        uint2 v;
        if (slot == 2) {
            v.x = __float_as_uint(h0[r]);
            v.y = 0u;                      // tag 0
        } else {
            v.x = 0u;
            v.y = 0xFFFFFFFFu;             // sentinel
        }
        recs[d] = v;
    }
}

// ---------------- Phase 1: Y = X @ Wi + bias (128x128 tile, 8x8/thread) ----
__global__ __launch_bounds__(256) void gemm_xwi(
    const float* __restrict__ X, const float* __restrict__ Wi,
    const float* __restrict__ bias, float* __restrict__ Y)
{
    __shared__ float As[16][132];            // transposed A tile [k][m], +4 pad
    __shared__ __align__(16) float Bs[16][128];
    const int tid = threadIdx.x;
    const int m0 = blockIdx.y * 128;
    const int n0 = blockIdx.x * 128;
    const int tx = tid & 15;                 // n-frag = tx*8
    const int ty = tid >> 4;                 // m-frag = ty*8
    const int ar = tid >> 2, ak = (tid & 3) * 4;   // A: rows ar, ar+64
    const int bk = tid >> 5, bn = (tid & 31) * 4;  // B: rows bk, bk+8

    float acc[8][8];
#pragma unroll
    for (int i = 0; i < 8; ++i)
#pragma unroll
        for (int j = 0; j < 8; ++j) acc[i][j] = 0.f;

    for (int kt = 0; kt < KDIM; kt += 16) {
        float4 a0 = *reinterpret_cast<const float4*>(&X[(size_t)(m0 + ar) * KDIM + kt + ak]);
        float4 a1 = *reinterpret_cast<const float4*>(&X[(size_t)(m0 + ar + 64) * KDIM + kt + ak]);
        float4 b0 = *reinterpret_cast<const float4*>(&Wi[(size_t)(kt + bk) * NG + n0 + bn]);
        float4 b1 = *reinterpret_cast<const float4*>(&Wi[(size_t)(kt + bk + 8) * NG + n0 + bn]);
        __syncthreads();
        As[ak + 0][ar] = a0.x; As[ak + 1][ar] = a0.y;
        As[ak + 2][ar] = a0.z; As[ak + 3][ar] = a0.w;
        As[ak + 0][ar + 64] = a1.x; As[ak + 1][ar + 64] = a1.y;
        As[ak + 2][ar + 64] = a1.z; As[ak + 3][ar + 64] = a1.w;
        *reinterpret_cast<float4*>(&Bs[bk][bn])     = b0;
        *reinterpret_cast<float4*>(&Bs[bk + 8][bn]) = b1;
        __syncthreads();
#pragma unroll
        for (int k = 0; k < 16; ++k) {
            float4 aA = *reinterpret_cast<const float4*>(&As[k][ty * 8]);
            float4 aB = *reinterpret_cast<const float4*>(&As[k][ty * 8 + 4]);
            float4 bA = *reinterpret_cast<const float4*>(&Bs[k][tx * 8]);
            float4 bB = *reinterpret_cast<const float4*>(&Bs[k][tx * 8 + 4]);
            float am[8] = { aA.x, aA.y, aA.z, aA.w, aB.x, aB.y, aB.z, aB.w };
            float bv[8] = { bA.x, bA.y, bA.z, bA.w, bB.x, bB.y, bB.z, bB.w };
#pragma unroll
            for (int i = 0; i < 8; ++i)
#pragma unroll
                for (int j = 0; j < 8; ++j)
                    acc[i][j] = fmaf(am[i], bv[j], acc[i][j]);
        }
    }
    float4 bb0 = *reinterpret_cast<const float4*>(&bias[n0 + tx * 8]);
    float4 bb1 = *reinterpret_cast<const float4*>(&bias[n0 + tx * 8 + 4]);
#pragma unroll
    for (int i = 0; i < 8; ++i) {
        float4 o0, o1;
        o0.x = acc[i][0] + bb0.x; o0.y = acc[i][1] + bb0.y;
        o0.z = acc[i][2] + bb0.z; o0.w = acc[i][3] + bb0.w;
        o1.x = acc[i][4] + bb1.x; o1.y = acc[i][5] + bb1.y;
        o1.z = acc[i][6] + bb1.z; o1.w = acc[i][7] + bb1.w;
        float* yr = &Y[(size_t)(m0 + ty * 8 + i) * NG + n0 + tx * 8];
        *reinterpret_cast<float4*>(yr)     = o0;
        *reinterpret_cast<float4*>(yr + 4) = o1;
    }
}

// ---------------- fast activations ----------------
__device__ __forceinline__ float fsigm(float x) { return 1.f / (1.f + __expf(-x)); }
__device__ __forceinline__ float ftanh(float x) {
    float ax = fabsf(x);
    float e  = __expf(2.f * ax);
    float t  = (e - 1.f) / (e + 1.f);
    t = (ax > 15.f) ? 1.f : t;
    return copysignf(t, x);
}

// ---------------- Phase 2: persistent recurrent kernel ----------------
// 256 blocks x 512 threads, cooperative, 1 block/CU.
//
// ROUND 7 = round-6 ownership structure + round-5 memory discipline.
// Wave w owns element e=b*8+w and ALL 4 of its gates (128 wt/lane, same
// count). Single barrier/step (hbuf double-buffered); each wave's lane 0
// activates + publishes right after its own in-wave reduce -- no gates
// LDS round-trip, no 2nd barrier, no serial 8-element epilogue.
// Fixes for round-6's scatter regression (FETCH +410MB, WRITE +248MB):
//  (1) Y read: tid<32 loads the block's 32 Y values as 4x32B contiguous
//      chunks (g=tid>>3,k=tid&7), relayed via 128B LDS. No 4B/8KB-stride
//      scalar reads.
//  (2) out write: lane0 drops hn into hstage[t&1][w]; at t+1 (after the
//      staging barrier, which orders it) tids 0-7 write row t-1 as one
//      32B coalesced chunk. Off the critical path.
//
// Sync protocol (round-5, unchanged): fused detect+fetch tag-polling of
// self-validating 8B records {h, tag=t+1}, global_store_dwordx2 sc0sc1
// (single-copy atomic), 3-slot rotation, fire-and-forget. Lap safety:
// all publishes follow the block-wide staging barrier, which follows all
// of the block's step-t polls; 3-slot chain argument as round 5.
__global__ __launch_bounds__(512)
__attribute__((amdgpu_waves_per_eu(2, 2)))
void lstm_persistent(
    const float* __restrict__ Y,     // [T][NG]
    const float* __restrict__ c0,
    const float* __restrict__ Wh,    // [K][NG]
    uint2* __restrict__ recs,        // [NSLOT][NREC] tagged h records
    float* __restrict__ out)         // [c_f][h_f][ys]
{
    const int b    = blockIdx.x;
    const int tid  = threadIdx.x;
    const int lane = tid & 63;
    const int w    = tid >> 6;       // 0..7 = owned h-element within block
    const int e    = b * 8 + w;      // global h index this wave owns

    __shared__ __align__(16) float hbuf[2][HDIM];   // 16 KiB double-buffered
    __shared__ float ylds[32];                      // Y relay (g*8+k)
    __shared__ float hstage[2][8];                  // deferred out-row

    // ---- one-time weight load: 4 gate-columns x 32 rows per lane ----
    // wc[j][g] = Wh[(64*j + lane)][g*2048 + e]
    float wc[32][4];
#pragma unroll
    for (int j = 0; j < 32; ++j) {
        const float* wp = &Wh[(size_t)(64 * j + lane) * NG + e];
        wc[j][0] = wp[0];
        wc[j][1] = wp[2048];
        wc[j][2] = wp[4096];
        wc[j][3] = wp[6144];
        asm volatile("" : "+v"(wc[j][0]), "+v"(wc[j][1]),
                          "+v"(wc[j][2]), "+v"(wc[j][3]));
    }

    float c_r = c0[e];     // live on lane 0 (others unused)
    float h_r = 0.f;
    __syncthreads();

    int rs = 2;   // read slot for step t = (t-1) mod 3 ; t=0 -> 2
    int ws = 0;   // write slot for step t = t mod 3

    for (int t = 0; t < T_STEPS; ++t) {
        // Y group load: tid<32 reads 4 contiguous 32B chunks (hidden
        // under the poll); ylds[g*8+k] = Y[t][g*2048 + b*8 + k]
        float yraw = 0.f;
        if (tid < 32)
            yraw = Y[(size_t)t * NG + ((tid >> 3) << 11) + (b << 3) + (tid & 7)];

        // ---- fused detect+fetch: tag-poll own 2x16B (= 4 records) ----
        float* hb = hbuf[t & 1];
        {
            const uint2* rb = recs + (size_t)rs * NREC;
            const uint2* p0 = rb + 2 * tid;          // records 2tid, 2tid+1
            const uint2* p1 = rb + 1024 + 2 * tid;   // records 1024+2tid, +1
            const unsigned expt = (unsigned)t;
            uint4 ra, rc;   // {h_a, tag_a, h_b, tag_b}
            for (;;) {
                asm volatile("global_load_dwordx4 %0, %2, off sc0 sc1\n\t"
                             "global_load_dwordx4 %1, %3, off sc0 sc1\n\t"
                             "s_waitcnt vmcnt(0)"
                             : "=&v"(ra), "=&v"(rc)
                             : "v"(p0), "v"(p1) : "memory");
                if (__all((ra.y == expt) & (ra.w == expt) &
                          (rc.y == expt) & (rc.w == expt))) break;
                __builtin_amdgcn_s_sleep(1);
            }
            float2 d0; d0.x = __uint_as_float(ra.x); d0.y = __uint_as_float(ra.z);
            float2 d1; d1.x = __uint_as_float(rc.x); d1.y = __uint_as_float(rc.z);
            *reinterpret_cast<float2*>(&hb[2 * tid])        = d0;
            *reinterpret_cast<float2*>(&hb[1024 + 2 * tid]) = d1;
        }
        if (tid < 32) ylds[tid] = yraw;
        __syncthreads();   // staging + ylds complete (ONLY barrier per step)

        // deferred coalesced out-row write for step t-1 (32B, wave 0)
        if (t > 0 && tid < 8)
            __builtin_nontemporal_store(hstage[(t - 1) & 1][tid],
                &out[2 * HDIM + (size_t)(t - 1) * HDIM + (b << 3) + tid]);

        // ---- 128 FMAs: 4 gate dot-products for element e ----
        float a0 = 0.f, a1 = 0.f, a2 = 0.f, a3 = 0.f;
#pragma unroll
        for (int j = 0; j < 32; ++j) {
            float hj = hb[64 * j + lane];     // 2-way bank alias: free
            a0 = fmaf(hj, wc[j][0], a0);
            a1 = fmaf(hj, wc[j][1], a1);
            a2 = fmaf(hj, wc[j][2], a2);
            a3 = fmaf(hj, wc[j][3], a3);
        }
#pragma unroll
        for (int off = 32; off >= 1; off >>= 1) {
            a0 += __shfl_xor(a0, off);
            a1 += __shfl_xor(a1, off);
            a2 += __shfl_xor(a2, off);
            a3 += __shfl_xor(a3, off);
        }
        // lanes 0-3 hold full sums; add gate's Y addend from relay
        float sg = ((lane == 0) ? a0 : (lane == 1) ? a1
                  : (lane == 2) ? a2 : a3)
                 + ((lane < 4) ? ylds[lane * 8 + w] : 0.f);
        float iv = __shfl(sg, 0);
        float fv = __shfl(sg, 1);
        float gv = __shfl(sg, 2);
        float ov = __shfl(sg, 3);

        // ---- per-wave epilogue: lane 0 activates + publishes, in
        //      parallel across the 8 waves ----
        if (lane == 0) {
            float cn = fsigm(fv) * c_r + fsigm(iv) * ftanh(gv);
            float hn = fsigm(ov) * ftanh(cn);
            c_r = cn;
            h_r = hn;
            hstage[t & 1][w] = hn;
            ull rec = ((ull)(unsigned)(t + 1) << 32) | (ull)__float_as_uint(hn);
            uint2* dst = recs + (size_t)ws * NREC + e;
            asm volatile("global_store_dwordx2 %0, %1, off sc0 sc1"
                         :: "v"(dst), "v"(rec) : "memory");
        }

        rs = ws;
        ws = (ws == 2) ? 0 : ws + 1;
    }

    __syncthreads();
    if (tid < 8)   // final ys row
        out[2 * HDIM + (size_t)(T_STEPS - 1) * HDIM + (b << 3) + tid] =
            hstage[(T_STEPS - 1) & 1][tid];
    if (lane == 0) {
        out[e]        = c_r;   // c_f
        out[HDIM + e] = h_r;   // h_f
    }
}

// ---------------- launch ----------------
extern "C" void kernel_launch(void* const* d_in, const int* in_sizes, int n_in,
                              void* d_out, int out_size, void* d_ws, size_t ws_size,
                              hipStream_t stream) {
    const float* x   = (const float*)d_in[0];
    const float* c0  = (const float*)d_in[1];
    const float* h0  = (const float*)d_in[2];
    const float* Wi  = (const float*)d_in[3];
    const float* Wh  = (const float*)d_in[4];
    const float* bia = (const float*)d_in[5];
    float* out = (float*)d_out;

    char* base = (char*)d_ws;
    float* Y = (float*)base;                                  // 128 MiB
    base += (size_t)T_STEPS * NG * sizeof(float);
    uint2* recs = (uint2*)base;                               // 48 KiB

    const int initN = NSLOT * NREC;
    hipLaunchKernelGGL(init_ws5, dim3((initN + 511) / 512), dim3(512), 0, stream,
                       h0, recs);
    hipLaunchKernelGGL(gemm_xwi, dim3(NG / 128, T_STEPS / 128), dim3(256), 0, stream,
                       x, Wi, bia, Y);

    void* args[] = { (void*)&Y, (void*)&c0, (void*)&Wh,
                     (void*)&recs, (void*)&out };
    (void)hipLaunchCooperativeKernel((const void*)lstm_persistent, dim3(256), dim3(512),
                                     args, 0, stream);
}

// Round 8
// 15132.086 us; speedup vs baseline: 1.6462x; 1.6462x over previous
//
#include <hip/hip_runtime.h>
#include <math.h>

#define T_STEPS 4096
#define HDIM    2048
#define KDIM    2048
#define NG      8192      // 4*H
#define NREC    2048      // records per slot: one {h,tag} per h element
#define NSLOT   3         // 3-slot rotation (lap safety without counters)

typedef unsigned long long ull;

// ---------------- init ----------------
// recs[3][NREC]: tagged h records, 8B each: {lo: h bits, hi: tag}.
// Producer of step t writes tag t+1 into slot t%3; consumer at step t
// polls slot (t-1)%3 for tag t. Slot 2 = h0 (tag 0); slots 0,1 sentinel.
__global__ void init_ws5(const float* __restrict__ h0,
                         uint2* __restrict__ recs) {    // [NSLOT][NREC]
    int d = blockIdx.x * blockDim.x + threadIdx.x;
    if (d < NSLOT * NREC) {
        int slot = d >> 11;          // NREC = 2048
        int r = d & (NREC - 1);
        uint2 v;
        if (slot == 2) {
            v.x = __float_as_uint(h0[r]);
            v.y = 0u;                      // tag 0
        } else {
            v.x = 0u;
            v.y = 0xFFFFFFFFu;             // sentinel
        }
        recs[d] = v;
    }
}

// ---------------- Phase 1: Y = X @ Wi + bias (128x128 tile, 8x8/thread) ----
__global__ __launch_bounds__(256) void gemm_xwi(
    const float* __restrict__ X, const float* __restrict__ Wi,
    const float* __restrict__ bias, float* __restrict__ Y)
{
    __shared__ float As[16][132];            // transposed A tile [k][m], +4 pad
    __shared__ __align__(16) float Bs[16][128];
    const int tid = threadIdx.x;
    const int m0 = blockIdx.y * 128;
    const int n0 = blockIdx.x * 128;
    const int tx = tid & 15;                 // n-frag = tx*8
    const int ty = tid >> 4;                 // m-frag = ty*8
    const int ar = tid >> 2, ak = (tid & 3) * 4;   // A: rows ar, ar+64
    const int bk = tid >> 5, bn = (tid & 31) * 4;  // B: rows bk, bk+8

    float acc[8][8];
#pragma unroll
    for (int i = 0; i < 8; ++i)
#pragma unroll
        for (int j = 0; j < 8; ++j) acc[i][j] = 0.f;

    for (int kt = 0; kt < KDIM; kt += 16) {
        float4 a0 = *reinterpret_cast<const float4*>(&X[(size_t)(m0 + ar) * KDIM + kt + ak]);
        float4 a1 = *reinterpret_cast<const float4*>(&X[(size_t)(m0 + ar + 64) * KDIM + kt + ak]);
        float4 b0 = *reinterpret_cast<const float4*>(&Wi[(size_t)(kt + bk) * NG + n0 + bn]);
        float4 b1 = *reinterpret_cast<const float4*>(&Wi[(size_t)(kt + bk + 8) * NG + n0 + bn]);
        __syncthreads();
        As[ak + 0][ar] = a0.x; As[ak + 1][ar] = a0.y;
        As[ak + 2][ar] = a0.z; As[ak + 3][ar] = a0.w;
        As[ak + 0][ar + 64] = a1.x; As[ak + 1][ar + 64] = a1.y;
        As[ak + 2][ar + 64] = a1.z; As[ak + 3][ar + 64] = a1.w;
        *reinterpret_cast<float4*>(&Bs[bk][bn])     = b0;
        *reinterpret_cast<float4*>(&Bs[bk + 8][bn]) = b1;
        __syncthreads();
#pragma unroll
        for (int k = 0; k < 16; ++k) {
            float4 aA = *reinterpret_cast<const float4*>(&As[k][ty * 8]);
            float4 aB = *reinterpret_cast<const float4*>(&As[k][ty * 8 + 4]);
            float4 bA = *reinterpret_cast<const float4*>(&Bs[k][tx * 8]);
            float4 bB = *reinterpret_cast<const float4*>(&Bs[k][tx * 8 + 4]);
            float am[8] = { aA.x, aA.y, aA.z, aA.w, aB.x, aB.y, aB.z, aB.w };
            float bv[8] = { bA.x, bA.y, bA.z, bA.w, bB.x, bB.y, bB.z, bB.w };
#pragma unroll
            for (int i = 0; i < 8; ++i)
#pragma unroll
                for (int j = 0; j < 8; ++j)
                    acc[i][j] = fmaf(am[i], bv[j], acc[i][j]);
        }
    }
    float4 bb0 = *reinterpret_cast<const float4*>(&bias[n0 + tx * 8]);
    float4 bb1 = *reinterpret_cast<const float4*>(&bias[n0 + tx * 8 + 4]);
#pragma unroll
    for (int i = 0; i < 8; ++i) {
        float4 o0, o1;
        o0.x = acc[i][0] + bb0.x; o0.y = acc[i][1] + bb0.y;
        o0.z = acc[i][2] + bb0.z; o0.w = acc[i][3] + bb0.w;
        o1.x = acc[i][4] + bb1.x; o1.y = acc[i][5] + bb1.y;
        o1.z = acc[i][6] + bb1.z; o1.w = acc[i][7] + bb1.w;
        float* yr = &Y[(size_t)(m0 + ty * 8 + i) * NG + n0 + tx * 8];
        *reinterpret_cast<float4*>(yr)     = o0;
        *reinterpret_cast<float4*>(yr + 4) = o1;
    }
}

// ---------------- fast activations ----------------
__device__ __forceinline__ float fsigm(float x) { return 1.f / (1.f + __expf(-x)); }
__device__ __forceinline__ float ftanh(float x) {
    float ax = fabsf(x);
    float e  = __expf(2.f * ax);
    float t  = (e - 1.f) / (e + 1.f);
    t = (ax > 15.f) ? 1.f : t;
    return copysignf(t, x);
}

// ---------------- Phase 2: persistent recurrent kernel ----------------
// 256 blocks x 1024 threads (16 waves), cooperative, 1 block/CU.
//
// ROUND 8: kill the weight spill. Every prior round had VGPR_Count=88
// with a 128-float/thread weight array -> per-step scratch reload tax
// (r5 cheapest at 32xdwordx4; r6/r7's 128xdword was the regression).
// Fix: 1024 threads/block halves the per-thread slice to 64 floats
// (16 float4), fitting the 128-VGPR budget at 4 waves/EU
// (waves_per_eu(4,4)). Per-thread FMAs and poll traffic also halve.
// Layout: 8 column-chunks (gate gg, half-elem hg; float4 wide) x
// 2 row-halves = 16 waves. Cross-half reduction via part[2][32] LDS.
//
// Sync protocol (round-5, unchanged): fused detect+fetch tag-polling of
// self-validating 8B records {h, tag=t+1}, published with a single
// global_store_dwordx2 sc0sc1 (aligned 64b = single-copy atomic),
// fire-and-forget, 3-slot rotation. Lap safety: publishes follow the
// part-barrier, which follows all of the block's step-t polls; 3-slot
// chain argument as round 5.
__global__ __launch_bounds__(1024)
__attribute__((amdgpu_waves_per_eu(4, 4)))
void lstm_persistent(
    const float* __restrict__ Y,     // [T][NG]
    const float* __restrict__ c0,
    const float* __restrict__ Wh,    // [K][NG]
    uint2* __restrict__ recs,        // [NSLOT][NREC] tagged h records
    float* __restrict__ out)         // [c_f][h_f][ys]
{
    const int b    = blockIdx.x;
    const int tid  = threadIdx.x;
    const int lane = tid & 63;
    const int w    = tid >> 6;       // 0..15
    const int c    = w >> 1;         // column-chunk 0..7
    const int half = w & 1;          // row half (0: rows 0-1023, 1: 1024-2047)
    const int gg   = c >> 1;         // gate
    const int hg   = c & 1;          // half-elem group (cols hg*4..hg*4+3)
    const int nbase = (gg << 11) + (b << 3) + (hg << 2);
    const int rowbase = (half << 10) + 4 * lane;

    __shared__ __align__(16) float hlds[HDIM];   // 8 KiB staging
    __shared__ float part[2][32];                // cross-half partials
    __shared__ float ylds[32];                   // Y relay (g*8+k)
    __shared__ float c_s[8];
    __shared__ float hlast[8];

    // ---- one-time weight load: 16 float4 per thread (64 VGPRs) ----
    float4 wreg[16];
#pragma unroll
    for (int j = 0; j < 4; ++j)
#pragma unroll
        for (int m = 0; m < 4; ++m) {
            const size_t k = (size_t)(rowbase + 256 * j + m);
            wreg[j * 4 + m] = *reinterpret_cast<const float4*>(&Wh[k * NG + nbase]);
        }
#pragma unroll
    for (int i = 0; i < 16; ++i) {
        asm volatile("" : "+v"(wreg[i].x), "+v"(wreg[i].y),
                          "+v"(wreg[i].z), "+v"(wreg[i].w));
    }

    if (tid < 8) c_s[tid] = c0[b * 8 + tid];
    __syncthreads();

    int rs = 2;   // read slot for step t = (t-1) mod 3 ; t=0 -> 2
    int ws_ = 0;  // write slot for step t = t mod 3

    for (int t = 0; t < T_STEPS; ++t) {
        // Y group load: tid<32 reads 4 contiguous 32B chunks (hidden
        // under the poll); ylds[g*8+k] = Y[t][g*2048 + b*8 + k]
        float yraw = 0.f;
        if (tid < 32)
            yraw = Y[(size_t)t * NG + ((tid >> 3) << 11) + (b << 3) + (tid & 7)];

        // ---- fused detect+fetch: tag-poll own 16B (= 2 records) ----
        {
            const uint2* p0 = recs + (size_t)rs * NREC + 2 * tid;
            const unsigned expt = (unsigned)t;
            uint4 ra;   // {h_a, tag_a, h_b, tag_b}
            for (;;) {
                asm volatile("global_load_dwordx4 %0, %1, off sc0 sc1\n\t"
                             "s_waitcnt vmcnt(0)"
                             : "=&v"(ra) : "v"(p0) : "memory");
                if (__all((ra.y == expt) & (ra.w == expt))) break;
                __builtin_amdgcn_s_sleep(1);
            }
            float2 d0; d0.x = __uint_as_float(ra.x); d0.y = __uint_as_float(ra.z);
            *reinterpret_cast<float2*>(&hlds[2 * tid]) = d0;
        }
        if (tid < 32) ylds[tid] = yraw;
        __syncthreads();   // barrier 1: staging + ylds complete

        // ---- 64 FMAs: this wave's half of 4 column dot-products ----
        float4 acc; acc.x = acc.y = acc.z = acc.w = 0.f;
        const float4* hb4 = reinterpret_cast<const float4*>(hlds);
#pragma unroll
        for (int j = 0; j < 4; ++j) {
            float4 h4 = hb4[(half << 8) + lane + (j << 6)];
            float4 w0 = wreg[4 * j + 0], w1 = wreg[4 * j + 1];
            float4 w2 = wreg[4 * j + 2], w3 = wreg[4 * j + 3];
            acc.x = fmaf(h4.x, w0.x, acc.x); acc.x = fmaf(h4.y, w1.x, acc.x);
            acc.x = fmaf(h4.z, w2.x, acc.x); acc.x = fmaf(h4.w, w3.x, acc.x);
            acc.y = fmaf(h4.x, w0.y, acc.y); acc.y = fmaf(h4.y, w1.y, acc.y);
            acc.y = fmaf(h4.z, w2.y, acc.y); acc.y = fmaf(h4.w, w3.y, acc.y);
            acc.z = fmaf(h4.x, w0.z, acc.z); acc.z = fmaf(h4.y, w1.z, acc.z);
            acc.z = fmaf(h4.z, w2.z, acc.z); acc.z = fmaf(h4.w, w3.z, acc.z);
            acc.w = fmaf(h4.x, w0.w, acc.w); acc.w = fmaf(h4.y, w1.w, acc.w);
            acc.w = fmaf(h4.z, w2.w, acc.w); acc.w = fmaf(h4.w, w3.w, acc.w);
        }
#pragma unroll
        for (int off = 32; off >= 1; off >>= 1) {
            acc.x += __shfl_xor(acc.x, off);
            acc.y += __shfl_xor(acc.y, off);
            acc.z += __shfl_xor(acc.z, off);
            acc.w += __shfl_xor(acc.w, off);
        }
        if (lane < 4) {
            float v = (lane == 0) ? acc.x : (lane == 1) ? acc.y
                    : (lane == 2) ? acc.z : acc.w;
            part[half][(c << 2) + lane] = v;   // index = gg*8 + hg*4 + lane
        }
        __syncthreads();   // barrier 2: partials ready; hlds reads done

        // ---- epilogue (tid<8): combine halves, activate, publish ----
        if (tid < 8) {
            float iv = part[0][tid]      + part[1][tid]      + ylds[tid];
            float fv = part[0][8 + tid]  + part[1][8 + tid]  + ylds[8 + tid];
            float gv = part[0][16 + tid] + part[1][16 + tid] + ylds[16 + tid];
            float ov = part[0][24 + tid] + part[1][24 + tid] + ylds[24 + tid];
            float cn = fsigm(fv) * c_s[tid] + fsigm(iv) * ftanh(gv);
            float hn = fsigm(ov) * ftanh(cn);
            c_s[tid] = cn;
            hlast[tid] = hn;
            // {lo: h bits, hi: tag t+1} -> one 64b store, single-copy atomic
            ull rec = ((ull)(unsigned)(t + 1) << 32) | (ull)__float_as_uint(hn);
            uint2* dst = recs + (size_t)ws_ * NREC + b * 8 + tid;
            asm volatile("global_store_dwordx2 %0, %1, off sc0 sc1"
                         :: "v"(dst), "v"(rec) : "memory");
            __builtin_nontemporal_store(hn, &out[2 * HDIM + (size_t)t * HDIM + b * 8 + tid]);
        }

        rs = ws_;
        ws_ = (ws_ == 2) ? 0 : ws_ + 1;
    }

    __syncthreads();
    if (tid < 8) {
        out[b * 8 + tid]        = c_s[tid];   // c_f
        out[HDIM + b * 8 + tid] = hlast[tid]; // h_f
    }
}

// ---------------- launch ----------------
extern "C" void kernel_launch(void* const* d_in, const int* in_sizes, int n_in,
                              void* d_out, int out_size, void* d_ws, size_t ws_size,
                              hipStream_t stream) {
    const float* x   = (const float*)d_in[0];
    const float* c0  = (const float*)d_in[1];
    const float* h0  = (const float*)d_in[2];
    const float* Wi  = (const float*)d_in[3];
    const float* Wh  = (const float*)d_in[4];
    const float* bia = (const float*)d_in[5];
    float* out = (float*)d_out;

    char* base = (char*)d_ws;
    float* Y = (float*)base;                                  // 128 MiB
    base += (size_t)T_STEPS * NG * sizeof(float);
    uint2* recs = (uint2*)base;                               // 48 KiB

    const int initN = NSLOT * NREC;
    hipLaunchKernelGGL(init_ws5, dim3((initN + 511) / 512), dim3(512), 0, stream,
                       h0, recs);
    hipLaunchKernelGGL(gemm_xwi, dim3(NG / 128, T_STEPS / 128), dim3(256), 0, stream,
                       x, Wi, bia, Y);

    void* args[] = { (void*)&Y, (void*)&c0, (void*)&Wh,
                     (void*)&recs, (void*)&out };
    (void)hipLaunchCooperativeKernel((const void*)lstm_persistent, dim3(256), dim3(1024),
                                     args, 0, stream);
}